// Round 5
// baseline (244.368 us; speedup 1.0000x reference)
//
#include <hip/hip_runtime.h>

// VectorQuantizer: x (32,64,64,64) f32, codebook (1024,64) f32
// out = concat( quantized (32,64,64,64) f32 , indices (32,64,64) as f32 )
//
// R11 = R10 + MFMA dependency-chain split (6-way ILP per wave).
//  - R10 post-mortem: 64us, MfmaUtil 30 / VALU 42 / LDS-conflict 0. Revised
//    pipe model (per-SIMD MFMA occupancy ~18.5cyc): MFMA pipe 24us, LDS pipe
//    ~20us, true VALU only ~7us per CU -> none saturated; limiter is the
//    6-deep dependent MFMA chain per M-tile (within-wave stall, matrix pipe
//    70% idle).
//  - CT_BODY now uses 3 independent 2-deep chains per tile (pa=Ak*B+Ci,
//    pb=Ah*R, pc=Ra*B), 6 accumulators in flight per ct, summed with 2
//    v_add_f32 per output before the int-key update (6 ops/output, VALU
//    still cheap). MFMA count unchanged (12/ct).
//  - regrouped f32 sums add <=~2 q-units rounding -> EPS_Q 20 -> 24.
//  - geometry/staging identical to R10: 4-ct chunks (16640B) dbuf, 4 blocks/
//    CU, grid 1024, global_load_lds staging, int keys, exact-f32 rescan net.

typedef _Float16 f16x8 __attribute__((ext_vector_type(8)));
typedef float    f32x4 __attribute__((ext_vector_type(4)));

#define VQ_D    64
#define VQ_HW   4096
#define VQ_NPOS 131072
#define SC      2048.0f
#define EPS_Q   24         // flag margin in q-units (24/2048 = 1.17e-2)
#define CHB     16640      // bytes per 4-ct chunk: 16KB B/R + 256B cn_q
#define CHBP    17664      // LDS buffer stride (CHB + 1KB pad)
// ws float offsets (stream = 16 chunks * 16640B = 266240B = 66560 floats)
#define WS_CBN  66560      // f32 cn[1024] (raw, for rescan)
#define WS_CBT  67584      // float4 cbT4[16384] (256 KB)
#define WS_CNT  133120     // int rescan counter
#define WS_LIST 133124     // int list[131072]

// ---------- prep ----------
// B item: it=(ct*4+s)*64+lane; s: 0=bh2 ks0, 1=bh2 ks1, 2=rb2k ks0, 3=rb2k ks1
// bh2 = -2*f16(b) (exact), rb2k = f16(-2*SC*(b - bh)).
// stream byte addr = (ct>>2)*CHB + (ct&3)*4096 + s*1024 + lane*16
// cn_q for code k=ct*16+i at (ct>>2)*CHB + 16384 + (ct&3)*64 + i*4 (=2048*cn)
__global__ __launch_bounds__(256)
void vq_prep(const float* __restrict__ cb, float* __restrict__ ws)
{
    const int tid = threadIdx.x;
    const int blk = blockIdx.x;
    if (blk < 64) {
        const int it   = blk * 256 + tid;            // [0, 16384)
        const int ct   = it >> 8;
        const int s    = (it >> 6) & 3;
        const int lane = it & 63;
        const int ks   = s & 1, isR = s >> 1;
        const int n    = ct * 16 + (lane & 15);      // code (B column)
        const int k0   = ks * 32 + (lane >> 4) * 8;  // dim  (B row)
        const float* src = cb + n * 64 + k0;
        f16x8 o;
        #pragma unroll
        for (int j = 0; j < 8; ++j) {
            const float b = src[j];
            const _Float16 bh = (_Float16)b;
            o[j] = isR ? (_Float16)((b - (float)bh) * (-2.0f * SC))
                       : (_Float16)(-2.0f * (float)bh);
        }
        *(f16x8*)((char*)ws + (size_t)(ct >> 2) * CHB + (ct & 3) * 4096
                            + s * 1024 + lane * 16) = o;
    } else if (blk < 128) {
        const int it = (blk - 64) * 256 + tid;       // [0, 16384)
        const int k = it >> 4, j4 = it & 15;
        ((float4*)(ws + WS_CBT))[j4 * 1024 + k] = ((const float4*)cb)[it];
    } else {
        const int k = (blk - 128) * 256 + tid;       // [0, 1024)
        const float4* row = (const float4*)(cb + k * 64);
        float a0 = 0.f, a1 = 0.f, a2 = 0.f, a3 = 0.f;
        #pragma unroll
        for (int j = 0; j < 16; ++j) {
            const float4 c = row[j];
            a0 = fmaf(c.x, c.x, a0); a1 = fmaf(c.y, c.y, a1);
            a2 = fmaf(c.z, c.z, a2); a3 = fmaf(c.w, c.w, a3);
        }
        const float cn = (a0 + a1) + (a2 + a3);
        ws[WS_CBN + k] = cn;                         // raw (rescan)
        const int ct = k >> 4, i = k & 15;
        *(float*)((char*)ws + (size_t)(ct >> 2) * CHB + 16384
                            + (ct & 3) * 64 + i * 4) = cn * 2048.0f;  // q-units
        if (k == 0) ((int*)ws)[WS_CNT] = 0;
    }
}

// ---------- main ----------
#define GLOAD_LDS(GP, LP)                                                     \
    __builtin_amdgcn_global_load_lds(                                         \
        (const __attribute__((address_space(1))) unsigned int*)(GP),          \
        (__attribute__((address_space(3))) unsigned int*)(LP), 16, 0, 0)

// stage one 16640B chunk at global GS (per-lane: +lane*16) into LDS at BOFF
#define STAGE(GS, BOFF)                                                       \
    {                                                                         \
        char* ld_ = (char*)bbuf + (BOFF) + wv * 1024;                         \
        const char* gs_ = (GS) + wv * 1024;                                   \
        GLOAD_LDS(gs_,         ld_);                                          \
        GLOAD_LDS(gs_ + 4096,  ld_ + 4096);                                   \
        GLOAD_LDS(gs_ + 8192,  ld_ + 8192);                                   \
        GLOAD_LDS(gs_ + 12288, ld_ + 12288);                                  \
        if (wv == 0 && lane < 16)                                             \
            GLOAD_LDS((GS) + 16384, (char*)bbuf + (BOFF) + 16384);            \
    }

// one 16-code tile: 3 independent 2-deep MFMA chains per M-tile (6 accs),
// partials summed by 2 VALU adds, then 4-VALU int-key top-2 update
#define CT_BODY(BOFF, SLOT, CTG)                                              \
    {                                                                         \
        const f16x8 B0 = *(const f16x8*)(lp + (BOFF) + (SLOT) * 4096);        \
        const f16x8 B1 = *(const f16x8*)(lp + (BOFF) + (SLOT) * 4096 + 1024); \
        const f16x8 R0 = *(const f16x8*)(lp + (BOFF) + (SLOT) * 4096 + 2048); \
        const f16x8 R1 = *(const f16x8*)(lp + (BOFF) + (SLOT) * 4096 + 3072); \
        const float cvq = *(const float*)(cp + (BOFF) + (SLOT) * 64);         \
        const f32x4 Ci = {cvq, cvq, cvq, cvq};                                \
        f32x4 pa0 = __builtin_amdgcn_mfma_f32_16x16x32_f16(Ak[0][0], B0, Ci,    0,0,0); \
        f32x4 pb0 = __builtin_amdgcn_mfma_f32_16x16x32_f16(Ah[0][0], R0, zero4, 0,0,0); \
        f32x4 pc0 = __builtin_amdgcn_mfma_f32_16x16x32_f16(Ra[0][0], B0, zero4, 0,0,0); \
        f32x4 pa1 = __builtin_amdgcn_mfma_f32_16x16x32_f16(Ak[1][0], B0, Ci,    0,0,0); \
        f32x4 pb1 = __builtin_amdgcn_mfma_f32_16x16x32_f16(Ah[1][0], R0, zero4, 0,0,0); \
        f32x4 pc1 = __builtin_amdgcn_mfma_f32_16x16x32_f16(Ra[1][0], B0, zero4, 0,0,0); \
        pa0 = __builtin_amdgcn_mfma_f32_16x16x32_f16(Ak[0][1], B1, pa0, 0,0,0); \
        pb0 = __builtin_amdgcn_mfma_f32_16x16x32_f16(Ah[0][1], R1, pb0, 0,0,0); \
        pc0 = __builtin_amdgcn_mfma_f32_16x16x32_f16(Ra[0][1], B1, pc0, 0,0,0); \
        pa1 = __builtin_amdgcn_mfma_f32_16x16x32_f16(Ak[1][1], B1, pa1, 0,0,0); \
        pb1 = __builtin_amdgcn_mfma_f32_16x16x32_f16(Ah[1][1], R1, pb1, 0,0,0); \
        pc1 = __builtin_amdgcn_mfma_f32_16x16x32_f16(Ra[1][1], B1, pc1, 0,0,0); \
        const int cbase_ = (CTG) * 16 + m;                                    \
        _Pragma("unroll")                                                     \
        for (int r = 0; r < 4; ++r) {                                         \
            const float q0_ = (pa0[r] + pb0[r]) + pc0[r];                     \
            const int k0_ = ((int)q0_ << 10) | cbase_;                        \
            int m0_;                                                          \
            asm("v_med3_i32 %0, %1, %2, %3"                                   \
                : "=v"(m0_) : "v"(k0_), "v"(d1[0][r]), "v"(d2[0][r]));        \
            d2[0][r] = m0_;                                                   \
            d1[0][r] = (k0_ < d1[0][r]) ? k0_ : d1[0][r];                     \
            const float q1_ = (pa1[r] + pb1[r]) + pc1[r];                     \
            const int k1_ = ((int)q1_ << 10) | cbase_;                        \
            int m1_;                                                          \
            asm("v_med3_i32 %0, %1, %2, %3"                                   \
                : "=v"(m1_) : "v"(k1_), "v"(d1[1][r]), "v"(d2[1][r]));        \
            d2[1][r] = m1_;                                                   \
            d1[1][r] = (k1_ < d1[1][r]) ? k1_ : d1[1][r];                     \
        }                                                                     \
    }

__global__ __launch_bounds__(256, 4)
void vq_main(const float* __restrict__ x,
             const float* __restrict__ cb,
             float* __restrict__ ws,
             float* __restrict__ out,
             float* __restrict__ idx_out)
{
    __shared__ f16x8 bbuf[2 * (CHBP / 16)];   // 2 padded 16.6KB chunks
    __shared__ int   sk[128];
    __shared__ int   smg[128];

    const int tid  = threadIdx.x;
    const int lane = tid & 63;
    const int wv   = tid >> 6;        // 4 waves, 32 positions each
    const int m    = lane & 15;
    const int q    = lane >> 4;

    const int p0 = blockIdx.x * 128;  // block: 128 consecutive positions
    const int b  = p0 >> 12;
    const int n0 = p0 & (VQ_HW - 1);
    const float* xw = x + (size_t)b * (VQ_D * VQ_HW) + n0 + wv * 32;

    const char* gs = (const char*)ws + lane * 16;   // per-lane stream cursor

    STAGE(gs, 0)                      // chunk 0 -> buf0 (hides under A build)

    // ---- A fragments: hi, 2048*hi (exact), scaled residual; 2 M-tiles ----
    f16x8 Ah[2][2], Ak[2][2], Ra[2][2];
    #pragma unroll
    for (int tl = 0; tl < 2; ++tl)
        #pragma unroll
        for (int ks = 0; ks < 2; ++ks) {
            f16x8 h8, k8, r8;
            #pragma unroll
            for (int j = 0; j < 8; ++j) {
                const float v = xw[(size_t)(ks * 32 + q * 8 + j) * VQ_HW + tl * 16 + m];
                const _Float16 vh = (_Float16)v;
                h8[j] = vh;
                k8[j] = (_Float16)((float)vh * 2048.0f);     // exact (pow2)
                r8[j] = (_Float16)((v - (float)vh) * SC);
            }
            Ah[tl][ks] = h8; Ak[tl][ks] = k8; Ra[tl][ks] = r8;
        }

    int d1[2][4], d2[2][4];
    #pragma unroll
    for (int tl = 0; tl < 2; ++tl)
        #pragma unroll
        for (int r = 0; r < 4; ++r) { d1[tl][r] = 0x7FFFFFFF; d2[tl][r] = 0x7FFFFFFF; }

    const f32x4 zero4 = {0.f, 0.f, 0.f, 0.f};
    const char* lp = (const char*)bbuf + lane * 16;        // B/R reads
    const char* cp = (const char*)bbuf + 16384 + m * 4;    // cn_q reads

    for (int it8 = 0; it8 < 8; ++it8) {     // 2 chunks (8 cts) per iteration
        const int cg = it8 * 8;
        __syncthreads();                    // chunk 2*it8 ready in buf0
        STAGE(gs + CHB, CHBP)               // chunk 2*it8+1 -> buf1
        CT_BODY(0, 0, cg + 0)
        CT_BODY(0, 1, cg + 1)
        CT_BODY(0, 2, cg + 2)
        CT_BODY(0, 3, cg + 3)
        __syncthreads();                    // chunk 2*it8+1 ready in buf1
        if (it8 < 7) STAGE(gs + 2 * CHB, 0) // chunk 2*it8+2 -> buf0
        CT_BODY(CHBP, 0, cg + 4)
        CT_BODY(CHBP, 1, cg + 5)
        CT_BODY(CHBP, 2, cg + 6)
        CT_BODY(CHBP, 3, cg + 7)
        gs += 2 * CHB;
    }

    // ---- top-2 merge across the 16 code-columns (keys carry the code) ----
    #pragma unroll
    for (int off = 1; off < 16; off <<= 1)
        #pragma unroll
        for (int tl = 0; tl < 2; ++tl)
            #pragma unroll
            for (int r = 0; r < 4; ++r) {
                const int od1 = __shfl_xor(d1[tl][r], off, 64);
                const int od2 = __shfl_xor(d2[tl][r], off, 64);
                const int mx  = (d1[tl][r] > od1) ? d1[tl][r] : od1;
                const int mn2 = (d2[tl][r] < od2) ? d2[tl][r] : od2;
                d2[tl][r] = (mx < mn2) ? mx : mn2;
                d1[tl][r] = (d1[tl][r] < od1) ? d1[tl][r] : od1;
            }

    if (m == 0) {
        #pragma unroll
        for (int tl = 0; tl < 2; ++tl)
            #pragma unroll
            for (int r = 0; r < 4; ++r) {
                const int li = wv * 32 + tl * 16 + q * 4 + r;
                sk[li]  = d1[tl][r] & 1023;
                smg[li] = (d2[tl][r] >> 10) - (d1[tl][r] >> 10);   // gap, q-units
            }
    }
    __syncthreads();

    // ---- epilogue: indices, rescan flags, quantized scatter ----
    const int pos  = tid & 127;
    const int half = tid >> 7;        // 2 threads per position, 32 dims each
    const int bk   = sk[pos];
    if (half == 0) {
        idx_out[p0 + pos] = (float)bk;
        if (smg[pos] < EPS_Q) {
            const int slot = atomicAdd((int*)ws + WS_CNT, 1);
            ((int*)ws)[WS_LIST + slot] = p0 + pos;
        }
    }
    const float4* cr = (const float4*)(cb + (size_t)bk * VQ_D) + half * 8;
    float* ob = out + (size_t)b * (VQ_D * VQ_HW) + (size_t)(half * 32) * VQ_HW + n0 + pos;
    #pragma unroll
    for (int d4 = 0; d4 < 8; ++d4) {
        const float4 v = cr[d4];
        ob[(size_t)(d4 * 4 + 0) * VQ_HW] = v.x;
        ob[(size_t)(d4 * 4 + 1) * VQ_HW] = v.y;
        ob[(size_t)(d4 * 4 + 2) * VQ_HW] = v.z;
        ob[(size_t)(d4 * 4 + 3) * VQ_HW] = v.w;
    }
}

// ---------- rescan: exact f32 argmin for flagged positions (verified) ----------
__global__ __launch_bounds__(64)
void vq_rescan(const float* __restrict__ x,
               const float* __restrict__ cb,
               const float* __restrict__ ws,
               float* __restrict__ out,
               float* __restrict__ idx_out)
{
    __shared__ float xs[VQ_D];
    const int lane = threadIdx.x;
    const int cnt  = ((const int*)ws)[WS_CNT];
    const int* list = (const int*)ws + WS_LIST;
    const float*  cnb  = ws + WS_CBN;
    const float4* cbT4 = (const float4*)(ws + WS_CBT);

    for (int i = blockIdx.x; i < cnt; i += gridDim.x) {
        const int p = list[i];
        const int b = p >> 12, n = p & (VQ_HW - 1);
        xs[lane] = x[(size_t)b * (VQ_D * VQ_HW) + (size_t)lane * VQ_HW + n];
        __syncthreads();
        float4 xr[16];
        #pragma unroll
        for (int j = 0; j < 16; ++j) xr[j] = ((const float4*)xs)[j];

        float bd = 3.4e38f; int bk = 0;
        #pragma unroll 4
        for (int t = 0; t < 16; ++t) {
            const int code = t * 64 + lane;           // per-lane ascending
            float a0 = 0.f, a1 = 0.f, a2 = 0.f, a3 = 0.f;
            #pragma unroll
            for (int j4 = 0; j4 < 16; ++j4) {
                const float4 c = cbT4[j4 * 1024 + code];   // coalesced
                a0 = fmaf(xr[j4].x, c.x, a0); a1 = fmaf(xr[j4].y, c.y, a1);
                a2 = fmaf(xr[j4].z, c.z, a2); a3 = fmaf(xr[j4].w, c.w, a3);
            }
            const float dist = fmaf(-2.0f, (a0 + a1) + (a2 + a3), cnb[code]);
            if (dist < bd) { bd = dist; bk = code; }
        }
        #pragma unroll
        for (int off = 1; off < 64; off <<= 1) {      // min dist, tie -> min k
            const float od = __shfl_xor(bd, off, 64);
            const int   ok = __shfl_xor(bk, off, 64);
            if (od < bd || (od == bd && ok < bk)) { bd = od; bk = ok; }
        }
        out[(size_t)b * (VQ_D * VQ_HW) + (size_t)lane * VQ_HW + n] = cb[(size_t)bk * VQ_D + lane];
        if (lane == 0) idx_out[p] = (float)bk;
        __syncthreads();
    }
}

extern "C" void kernel_launch(void* const* d_in, const int* in_sizes, int n_in,
                              void* d_out, int out_size, void* d_ws, size_t ws_size,
                              hipStream_t stream) {
    const float* x  = (const float*)d_in[0];
    const float* cb = (const float*)d_in[1];
    float* out = (float*)d_out;
    float* idx = out + (size_t)VQ_NPOS * VQ_D;   // 8,388,608 floats in
    float* ws  = (float*)d_ws;                    // ~1.06 MB used

    vq_prep  <<<dim3(132),  dim3(256), 0, stream>>>(cb, ws);
    vq_main  <<<dim3(1024), dim3(256), 0, stream>>>(x, cb, ws, out, idx);
    vq_rescan<<<dim3(1024), dim3(64),  0, stream>>>(x, cb, ws, out, idx);
}

// Round 6
// 160.178 us; speedup vs baseline: 1.5256x; 1.5256x over previous
//
#include <hip/hip_runtime.h>

// VectorQuantizer: x (32,64,64,64) f32, codebook (1024,64) f32
// out = concat( quantized (32,64,64,64) f32 , indices (32,64,64) as f32 )
//
// R12 = R10 + BOUNDED chain split (retry of R11's idea minus the spill).
//  - R11 post-mortem: FETCH 18.5->284MB, WRITE 33->121MB = scratch spill
//    (~1KB/thread) -- post-unroll the scheduler interleaved 4 CT_BODYs x 6
//    accs = up to 24 f32x4 live -> spill + L3 thrash. ILP theory untested.
//  - R12: 4 accs (2 per M-tile, split by K-half): pa = Ci + Ak0*B0 + Ah0*R0
//    + Ra0*B0, pb = Ak1*B1 + Ah1*R1 + Ra1*B1; depth 3, one add per output.
//    Same 12 MFMAs, same products, regrouping error <= ~1 q-unit (EPS_Q 24).
//  - sched_barrier(0x100 = DS_READ may cross) after each CT_BODY: next
//    body's LDS loads still hoist (latency hidden) but MFMA/VALU cannot
//    interleave across bodies -> live accs bounded, no spill.
//  - geometry/staging/prep/rescan byte-identical to R10 (verified 64us main,
//    FETCH 18.5MB, absmax 0).

typedef _Float16 f16x8 __attribute__((ext_vector_type(8)));
typedef float    f32x4 __attribute__((ext_vector_type(4)));

#define VQ_D    64
#define VQ_HW   4096
#define VQ_NPOS 131072
#define SC      2048.0f
#define EPS_Q   24         // flag margin in q-units (24/2048 = 1.17e-2)
#define CHB     16640      // bytes per 4-ct chunk: 16KB B/R + 256B cn_q
#define CHBP    17664      // LDS buffer stride (CHB + 1KB pad)
// ws float offsets (stream = 16 chunks * 16640B = 266240B = 66560 floats)
#define WS_CBN  66560      // f32 cn[1024] (raw, for rescan)
#define WS_CBT  67584      // float4 cbT4[16384] (256 KB)
#define WS_CNT  133120     // int rescan counter
#define WS_LIST 133124     // int list[131072]

// ---------- prep ----------
// B item: it=(ct*4+s)*64+lane; s: 0=bh2 ks0, 1=bh2 ks1, 2=rb2k ks0, 3=rb2k ks1
// bh2 = -2*f16(b) (exact), rb2k = f16(-2*SC*(b - bh)).
// stream byte addr = (ct>>2)*CHB + (ct&3)*4096 + s*1024 + lane*16
// cn_q for code k=ct*16+i at (ct>>2)*CHB + 16384 + (ct&3)*64 + i*4 (=2048*cn)
__global__ __launch_bounds__(256)
void vq_prep(const float* __restrict__ cb, float* __restrict__ ws)
{
    const int tid = threadIdx.x;
    const int blk = blockIdx.x;
    if (blk < 64) {
        const int it   = blk * 256 + tid;            // [0, 16384)
        const int ct   = it >> 8;
        const int s    = (it >> 6) & 3;
        const int lane = it & 63;
        const int ks   = s & 1, isR = s >> 1;
        const int n    = ct * 16 + (lane & 15);      // code (B column)
        const int k0   = ks * 32 + (lane >> 4) * 8;  // dim  (B row)
        const float* src = cb + n * 64 + k0;
        f16x8 o;
        #pragma unroll
        for (int j = 0; j < 8; ++j) {
            const float b = src[j];
            const _Float16 bh = (_Float16)b;
            o[j] = isR ? (_Float16)((b - (float)bh) * (-2.0f * SC))
                       : (_Float16)(-2.0f * (float)bh);
        }
        *(f16x8*)((char*)ws + (size_t)(ct >> 2) * CHB + (ct & 3) * 4096
                            + s * 1024 + lane * 16) = o;
    } else if (blk < 128) {
        const int it = (blk - 64) * 256 + tid;       // [0, 16384)
        const int k = it >> 4, j4 = it & 15;
        ((float4*)(ws + WS_CBT))[j4 * 1024 + k] = ((const float4*)cb)[it];
    } else {
        const int k = (blk - 128) * 256 + tid;       // [0, 1024)
        const float4* row = (const float4*)(cb + k * 64);
        float a0 = 0.f, a1 = 0.f, a2 = 0.f, a3 = 0.f;
        #pragma unroll
        for (int j = 0; j < 16; ++j) {
            const float4 c = row[j];
            a0 = fmaf(c.x, c.x, a0); a1 = fmaf(c.y, c.y, a1);
            a2 = fmaf(c.z, c.z, a2); a3 = fmaf(c.w, c.w, a3);
        }
        const float cn = (a0 + a1) + (a2 + a3);
        ws[WS_CBN + k] = cn;                         // raw (rescan)
        const int ct = k >> 4, i = k & 15;
        *(float*)((char*)ws + (size_t)(ct >> 2) * CHB + 16384
                            + (ct & 3) * 64 + i * 4) = cn * 2048.0f;  // q-units
        if (k == 0) ((int*)ws)[WS_CNT] = 0;
    }
}

// ---------- main ----------
#define GLOAD_LDS(GP, LP)                                                     \
    __builtin_amdgcn_global_load_lds(                                         \
        (const __attribute__((address_space(1))) unsigned int*)(GP),          \
        (__attribute__((address_space(3))) unsigned int*)(LP), 16, 0, 0)

// stage one 16640B chunk at global GS (per-lane: +lane*16) into LDS at BOFF
#define STAGE(GS, BOFF)                                                       \
    {                                                                         \
        char* ld_ = (char*)bbuf + (BOFF) + wv * 1024;                         \
        const char* gs_ = (GS) + wv * 1024;                                   \
        GLOAD_LDS(gs_,         ld_);                                          \
        GLOAD_LDS(gs_ + 4096,  ld_ + 4096);                                   \
        GLOAD_LDS(gs_ + 8192,  ld_ + 8192);                                   \
        GLOAD_LDS(gs_ + 12288, ld_ + 12288);                                  \
        if (wv == 0 && lane < 16)                                             \
            GLOAD_LDS((GS) + 16384, (char*)bbuf + (BOFF) + 16384);            \
    }

// one 16-code tile: 4 independent depth-3 MFMA chains (2 per M-tile, split
// by K-half), 1 add + 4-VALU int-key update per output.
// sched_barrier(DS_READ) at the end bounds accumulator live ranges to the
// body (anti-spill) while still letting the next body's LDS loads hoist.
#define CT_BODY(BOFF, SLOT, CTG)                                              \
    {                                                                         \
        const f16x8 B0 = *(const f16x8*)(lp + (BOFF) + (SLOT) * 4096);        \
        const f16x8 B1 = *(const f16x8*)(lp + (BOFF) + (SLOT) * 4096 + 1024); \
        const f16x8 R0 = *(const f16x8*)(lp + (BOFF) + (SLOT) * 4096 + 2048); \
        const f16x8 R1 = *(const f16x8*)(lp + (BOFF) + (SLOT) * 4096 + 3072); \
        const float cvq = *(const float*)(cp + (BOFF) + (SLOT) * 64);         \
        const f32x4 Ci = {cvq, cvq, cvq, cvq};                                \
        f32x4 pa0 = __builtin_amdgcn_mfma_f32_16x16x32_f16(Ak[0][0], B0, Ci,    0,0,0); \
        f32x4 pb0 = __builtin_amdgcn_mfma_f32_16x16x32_f16(Ak[0][1], B1, zero4, 0,0,0); \
        f32x4 pa1 = __builtin_amdgcn_mfma_f32_16x16x32_f16(Ak[1][0], B0, Ci,    0,0,0); \
        f32x4 pb1 = __builtin_amdgcn_mfma_f32_16x16x32_f16(Ak[1][1], B1, zero4, 0,0,0); \
        pa0 = __builtin_amdgcn_mfma_f32_16x16x32_f16(Ah[0][0], R0, pa0, 0,0,0); \
        pb0 = __builtin_amdgcn_mfma_f32_16x16x32_f16(Ah[0][1], R1, pb0, 0,0,0); \
        pa1 = __builtin_amdgcn_mfma_f32_16x16x32_f16(Ah[1][0], R0, pa1, 0,0,0); \
        pb1 = __builtin_amdgcn_mfma_f32_16x16x32_f16(Ah[1][1], R1, pb1, 0,0,0); \
        pa0 = __builtin_amdgcn_mfma_f32_16x16x32_f16(Ra[0][0], B0, pa0, 0,0,0); \
        pb0 = __builtin_amdgcn_mfma_f32_16x16x32_f16(Ra[0][1], B1, pb0, 0,0,0); \
        pa1 = __builtin_amdgcn_mfma_f32_16x16x32_f16(Ra[1][0], B0, pa1, 0,0,0); \
        pb1 = __builtin_amdgcn_mfma_f32_16x16x32_f16(Ra[1][1], B1, pb1, 0,0,0); \
        const int cbase_ = (CTG) * 16 + m;                                    \
        _Pragma("unroll")                                                     \
        for (int r = 0; r < 4; ++r) {                                         \
            const float q0_ = pa0[r] + pb0[r];                                \
            const int k0_ = ((int)q0_ << 10) | cbase_;                        \
            int m0_;                                                          \
            asm("v_med3_i32 %0, %1, %2, %3"                                   \
                : "=v"(m0_) : "v"(k0_), "v"(d1[0][r]), "v"(d2[0][r]));        \
            d2[0][r] = m0_;                                                   \
            d1[0][r] = (k0_ < d1[0][r]) ? k0_ : d1[0][r];                     \
            const float q1_ = pa1[r] + pb1[r];                                \
            const int k1_ = ((int)q1_ << 10) | cbase_;                        \
            int m1_;                                                          \
            asm("v_med3_i32 %0, %1, %2, %3"                                   \
                : "=v"(m1_) : "v"(k1_), "v"(d1[1][r]), "v"(d2[1][r]));        \
            d2[1][r] = m1_;                                                   \
            d1[1][r] = (k1_ < d1[1][r]) ? k1_ : d1[1][r];                     \
        }                                                                     \
        __builtin_amdgcn_sched_barrier(0x100);  /* only DS_READ may cross */  \
    }

__global__ __launch_bounds__(256, 4)
void vq_main(const float* __restrict__ x,
             const float* __restrict__ cb,
             float* __restrict__ ws,
             float* __restrict__ out,
             float* __restrict__ idx_out)
{
    __shared__ f16x8 bbuf[2 * (CHBP / 16)];   // 2 padded 16.6KB chunks
    __shared__ int   sk[128];
    __shared__ int   smg[128];

    const int tid  = threadIdx.x;
    const int lane = tid & 63;
    const int wv   = tid >> 6;        // 4 waves, 32 positions each
    const int m    = lane & 15;
    const int q    = lane >> 4;

    const int p0 = blockIdx.x * 128;  // block: 128 consecutive positions
    const int b  = p0 >> 12;
    const int n0 = p0 & (VQ_HW - 1);
    const float* xw = x + (size_t)b * (VQ_D * VQ_HW) + n0 + wv * 32;

    const char* gs = (const char*)ws + lane * 16;   // per-lane stream cursor

    STAGE(gs, 0)                      // chunk 0 -> buf0 (hides under A build)

    // ---- A fragments: hi, 2048*hi (exact), scaled residual; 2 M-tiles ----
    f16x8 Ah[2][2], Ak[2][2], Ra[2][2];
    #pragma unroll
    for (int tl = 0; tl < 2; ++tl)
        #pragma unroll
        for (int ks = 0; ks < 2; ++ks) {
            f16x8 h8, k8, r8;
            #pragma unroll
            for (int j = 0; j < 8; ++j) {
                const float v = xw[(size_t)(ks * 32 + q * 8 + j) * VQ_HW + tl * 16 + m];
                const _Float16 vh = (_Float16)v;
                h8[j] = vh;
                k8[j] = (_Float16)((float)vh * 2048.0f);     // exact (pow2)
                r8[j] = (_Float16)((v - (float)vh) * SC);
            }
            Ah[tl][ks] = h8; Ak[tl][ks] = k8; Ra[tl][ks] = r8;
        }

    int d1[2][4], d2[2][4];
    #pragma unroll
    for (int tl = 0; tl < 2; ++tl)
        #pragma unroll
        for (int r = 0; r < 4; ++r) { d1[tl][r] = 0x7FFFFFFF; d2[tl][r] = 0x7FFFFFFF; }

    const f32x4 zero4 = {0.f, 0.f, 0.f, 0.f};
    const char* lp = (const char*)bbuf + lane * 16;        // B/R reads
    const char* cp = (const char*)bbuf + 16384 + m * 4;    // cn_q reads

    for (int it8 = 0; it8 < 8; ++it8) {     // 2 chunks (8 cts) per iteration
        const int cg = it8 * 8;
        __syncthreads();                    // chunk 2*it8 ready in buf0
        STAGE(gs + CHB, CHBP)               // chunk 2*it8+1 -> buf1
        CT_BODY(0, 0, cg + 0)
        CT_BODY(0, 1, cg + 1)
        CT_BODY(0, 2, cg + 2)
        CT_BODY(0, 3, cg + 3)
        __syncthreads();                    // chunk 2*it8+1 ready in buf1
        if (it8 < 7) STAGE(gs + 2 * CHB, 0) // chunk 2*it8+2 -> buf0
        CT_BODY(CHBP, 0, cg + 4)
        CT_BODY(CHBP, 1, cg + 5)
        CT_BODY(CHBP, 2, cg + 6)
        CT_BODY(CHBP, 3, cg + 7)
        gs += 2 * CHB;
    }

    // ---- top-2 merge across the 16 code-columns (keys carry the code) ----
    #pragma unroll
    for (int off = 1; off < 16; off <<= 1)
        #pragma unroll
        for (int tl = 0; tl < 2; ++tl)
            #pragma unroll
            for (int r = 0; r < 4; ++r) {
                const int od1 = __shfl_xor(d1[tl][r], off, 64);
                const int od2 = __shfl_xor(d2[tl][r], off, 64);
                const int mx  = (d1[tl][r] > od1) ? d1[tl][r] : od1;
                const int mn2 = (d2[tl][r] < od2) ? d2[tl][r] : od2;
                d2[tl][r] = (mx < mn2) ? mx : mn2;
                d1[tl][r] = (d1[tl][r] < od1) ? d1[tl][r] : od1;
            }

    if (m == 0) {
        #pragma unroll
        for (int tl = 0; tl < 2; ++tl)
            #pragma unroll
            for (int r = 0; r < 4; ++r) {
                const int li = wv * 32 + tl * 16 + q * 4 + r;
                sk[li]  = d1[tl][r] & 1023;
                smg[li] = (d2[tl][r] >> 10) - (d1[tl][r] >> 10);   // gap, q-units
            }
    }
    __syncthreads();

    // ---- epilogue: indices, rescan flags, quantized scatter ----
    const int pos  = tid & 127;
    const int half = tid >> 7;        // 2 threads per position, 32 dims each
    const int bk   = sk[pos];
    if (half == 0) {
        idx_out[p0 + pos] = (float)bk;
        if (smg[pos] < EPS_Q) {
            const int slot = atomicAdd((int*)ws + WS_CNT, 1);
            ((int*)ws)[WS_LIST + slot] = p0 + pos;
        }
    }
    const float4* cr = (const float4*)(cb + (size_t)bk * VQ_D) + half * 8;
    float* ob = out + (size_t)b * (VQ_D * VQ_HW) + (size_t)(half * 32) * VQ_HW + n0 + pos;
    #pragma unroll
    for (int d4 = 0; d4 < 8; ++d4) {
        const float4 v = cr[d4];
        ob[(size_t)(d4 * 4 + 0) * VQ_HW] = v.x;
        ob[(size_t)(d4 * 4 + 1) * VQ_HW] = v.y;
        ob[(size_t)(d4 * 4 + 2) * VQ_HW] = v.z;
        ob[(size_t)(d4 * 4 + 3) * VQ_HW] = v.w;
    }
}

// ---------- rescan: exact f32 argmin for flagged positions (verified) ----------
__global__ __launch_bounds__(64)
void vq_rescan(const float* __restrict__ x,
               const float* __restrict__ cb,
               const float* __restrict__ ws,
               float* __restrict__ out,
               float* __restrict__ idx_out)
{
    __shared__ float xs[VQ_D];
    const int lane = threadIdx.x;
    const int cnt  = ((const int*)ws)[WS_CNT];
    const int* list = (const int*)ws + WS_LIST;
    const float*  cnb  = ws + WS_CBN;
    const float4* cbT4 = (const float4*)(ws + WS_CBT);

    for (int i = blockIdx.x; i < cnt; i += gridDim.x) {
        const int p = list[i];
        const int b = p >> 12, n = p & (VQ_HW - 1);
        xs[lane] = x[(size_t)b * (VQ_D * VQ_HW) + (size_t)lane * VQ_HW + n];
        __syncthreads();
        float4 xr[16];
        #pragma unroll
        for (int j = 0; j < 16; ++j) xr[j] = ((const float4*)xs)[j];

        float bd = 3.4e38f; int bk = 0;
        #pragma unroll 4
        for (int t = 0; t < 16; ++t) {
            const int code = t * 64 + lane;           // per-lane ascending
            float a0 = 0.f, a1 = 0.f, a2 = 0.f, a3 = 0.f;
            #pragma unroll
            for (int j4 = 0; j4 < 16; ++j4) {
                const float4 c = cbT4[j4 * 1024 + code];   // coalesced
                a0 = fmaf(xr[j4].x, c.x, a0); a1 = fmaf(xr[j4].y, c.y, a1);
                a2 = fmaf(xr[j4].z, c.z, a2); a3 = fmaf(xr[j4].w, c.w, a3);
            }
            const float dist = fmaf(-2.0f, (a0 + a1) + (a2 + a3), cnb[code]);
            if (dist < bd) { bd = dist; bk = code; }
        }
        #pragma unroll
        for (int off = 1; off < 64; off <<= 1) {      // min dist, tie -> min k
            const float od = __shfl_xor(bd, off, 64);
            const int   ok = __shfl_xor(bk, off, 64);
            if (od < bd || (od == bd && ok < bk)) { bd = od; bk = ok; }
        }
        out[(size_t)b * (VQ_D * VQ_HW) + (size_t)lane * VQ_HW + n] = cb[(size_t)bk * VQ_D + lane];
        if (lane == 0) idx_out[p] = (float)bk;
        __syncthreads();
    }
}

extern "C" void kernel_launch(void* const* d_in, const int* in_sizes, int n_in,
                              void* d_out, int out_size, void* d_ws, size_t ws_size,
                              hipStream_t stream) {
    const float* x  = (const float*)d_in[0];
    const float* cb = (const float*)d_in[1];
    float* out = (float*)d_out;
    float* idx = out + (size_t)VQ_NPOS * VQ_D;   // 8,388,608 floats in
    float* ws  = (float*)d_ws;                    // ~1.06 MB used

    vq_prep  <<<dim3(132),  dim3(256), 0, stream>>>(cb, ws);
    vq_main  <<<dim3(1024), dim3(256), 0, stream>>>(x, cb, ws, out, idx);
    vq_rescan<<<dim3(1024), dim3(64),  0, stream>>>(x, cb, ws, out, idx);
}

// Round 8
// 158.538 us; speedup vs baseline: 1.5414x; 1.0103x over previous
//
#include <hip/hip_runtime.h>

// VectorQuantizer: x (32,64,64,64) f32, codebook (1024,64) f32
// out = concat( quantized (32,64,64,64) f32 , indices (32,64,64) as f32 )
//
// R13b = R13 resubmitted unchanged (R7 bench died at container level with no
// verify/counters; kernel audit found no hang mechanism: vmcnt accounting
// exact, wait-before-barrier, symmetric waves, no VMEM in ring loop).
//
// R13 = R12's verified math + counted-vmcnt ring pipeline (T3/T4/T5).
//  - R12 post-mortem: clean counters (no spill), chain split -> NO MfmaUtil
//    gain (30->31) => ILP theory falsified. Revised model closes: VALUBusy
//    includes MFMA issue (24.8us MFMA + 9.6us VALU = 50% ~ measured 47%);
//    pipes idle half the time. Structure = m97 2-barrier shape whose
//    __syncthreads vmcnt(0)-drain is the documented ~20% stall; cure is
//    counted vmcnt crossing barriers (T3/T4, +28-41% on GEMM) + setprio (T5).
//  - chunk = 2 ct = 8KB, cn_q in separate 4KB LDS (loaded once) -> uniform
//    2 gloads/wave/chunk. Ring of 4 slots (32KB) + cn 4KB -> 4 blocks/CU.
//  - per iter: s_waitcnt vmcnt(4); s_barrier; stage chunk t+3; 2 CT_BODYs.
//    No vmcnt(0) in main loop; tail peel vmcnt(4)/2/0. waitcnt BEFORE
//    barrier => all waves' chunk-t loads visible; stage slot (t+3)&3 last
//    read at t-1, separated by this barrier.
//  - setprio(1) around each 12-MFMA cluster; sched_barrier(0x100) per body
//    (anti-spill fence, verified R12, VGPR 60).
//  - numerics bit-identical to R12 (absmax 0): q-unit int keys, EPS_Q 24,
//    exact-f32 rescan.

typedef _Float16 f16x8 __attribute__((ext_vector_type(8)));
typedef float    f32x4 __attribute__((ext_vector_type(4)));

#define VQ_D    64
#define VQ_HW   4096
#define VQ_NPOS 131072
#define SC      2048.0f
#define EPS_Q   24         // flag margin in q-units (24/2048 = 1.17e-2)
// ws float offsets (stream = 32 chunks * 8192B = 256KB = 65536 floats)
#define WS_CBN  65536      // f32 cn[1024] raw (rescan)
#define WS_CNQ  66560      // f32 cn_q[1024] = 2048*cn (main C-init)
#define WS_CBT  67584      // float4 cbT4[16384] (256 KB)
#define WS_CNT  133120     // int rescan counter
#define WS_LIST 133124     // int list[131072]

// ---------- prep ----------
// B item: it=(ct*4+s)*64+lane; s: 0=bh2 ks0, 1=bh2 ks1, 2=rb2k ks0, 3=rb2k ks1
// bh2 = -2*f16(b) (exact), rb2k = f16(-2*SC*(b - bh)).
// byte addr = ct*4096 + s*1024 + lane*16; chunk c = cts {2c,2c+1} = 8KB.
__global__ __launch_bounds__(256)
void vq_prep(const float* __restrict__ cb, float* __restrict__ ws)
{
    const int tid = threadIdx.x;
    const int blk = blockIdx.x;
    if (blk < 64) {
        const int it   = blk * 256 + tid;            // [0, 16384)
        const int ct   = it >> 8;
        const int s    = (it >> 6) & 3;
        const int lane = it & 63;
        const int ks   = s & 1, isR = s >> 1;
        const int n    = ct * 16 + (lane & 15);      // code (B column)
        const int k0   = ks * 32 + (lane >> 4) * 8;  // dim  (B row)
        const float* src = cb + n * 64 + k0;
        f16x8 o;
        #pragma unroll
        for (int j = 0; j < 8; ++j) {
            const float b = src[j];
            const _Float16 bh = (_Float16)b;
            o[j] = isR ? (_Float16)((b - (float)bh) * (-2.0f * SC))
                       : (_Float16)(-2.0f * (float)bh);
        }
        ((f16x8*)ws)[it] = o;
    } else if (blk < 128) {
        const int it = (blk - 64) * 256 + tid;       // [0, 16384)
        const int k = it >> 4, j4 = it & 15;
        ((float4*)(ws + WS_CBT))[j4 * 1024 + k] = ((const float4*)cb)[it];
    } else {
        const int k = (blk - 128) * 256 + tid;       // [0, 1024)
        const float4* row = (const float4*)(cb + k * 64);
        float a0 = 0.f, a1 = 0.f, a2 = 0.f, a3 = 0.f;
        #pragma unroll
        for (int j = 0; j < 16; ++j) {
            const float4 c = row[j];
            a0 = fmaf(c.x, c.x, a0); a1 = fmaf(c.y, c.y, a1);
            a2 = fmaf(c.z, c.z, a2); a3 = fmaf(c.w, c.w, a3);
        }
        const float cn = (a0 + a1) + (a2 + a3);
        ws[WS_CBN + k] = cn;                         // raw (rescan)
        ws[WS_CNQ + k] = cn * 2048.0f;               // q-units (main)
        if (k == 0) ((int*)ws)[WS_CNT] = 0;
    }
}

// ---------- main ----------
#define GLOAD_LDS(GP, LP)                                                     \
    __builtin_amdgcn_global_load_lds(                                         \
        (const __attribute__((address_space(1))) unsigned int*)(GP),          \
        (__attribute__((address_space(3))) unsigned int*)(LP), 16, 0, 0)

// stage 8KB chunk CK into ring slot byte-offset BOFF: 2 gloads per wave
#define STAGE2(CK, BOFF)                                                      \
    {                                                                         \
        const char* gs_ = (const char*)ws + (size_t)(CK) * 8192               \
                          + wv * 2048 + lane * 16;                            \
        char* ld_ = (char*)bbuf + (BOFF) + wv * 2048;                         \
        GLOAD_LDS(gs_, ld_);                                                  \
        GLOAD_LDS(gs_ + 1024, ld_ + 1024);                                    \
    }

// one 16-code tile (R12's verified math): 4 depth-3 chains, setprio-wrapped
#define CT_BODY(BOFF, CI, CTG)                                                \
    {                                                                         \
        const f16x8 B0 = *(const f16x8*)(lp + (BOFF) + (CI) * 4096);          \
        const f16x8 B1 = *(const f16x8*)(lp + (BOFF) + (CI) * 4096 + 1024);   \
        const f16x8 R0 = *(const f16x8*)(lp + (BOFF) + (CI) * 4096 + 2048);   \
        const f16x8 R1 = *(const f16x8*)(lp + (BOFF) + (CI) * 4096 + 3072);   \
        const float cvq = cnq_lds[(CTG) * 16 + m];                            \
        const f32x4 Ci = {cvq, cvq, cvq, cvq};                                \
        __builtin_amdgcn_s_setprio(1);                                        \
        f32x4 pa0 = __builtin_amdgcn_mfma_f32_16x16x32_f16(Ak[0][0], B0, Ci,    0,0,0); \
        f32x4 pb0 = __builtin_amdgcn_mfma_f32_16x16x32_f16(Ak[0][1], B1, zero4, 0,0,0); \
        f32x4 pa1 = __builtin_amdgcn_mfma_f32_16x16x32_f16(Ak[1][0], B0, Ci,    0,0,0); \
        f32x4 pb1 = __builtin_amdgcn_mfma_f32_16x16x32_f16(Ak[1][1], B1, zero4, 0,0,0); \
        pa0 = __builtin_amdgcn_mfma_f32_16x16x32_f16(Ah[0][0], R0, pa0, 0,0,0); \
        pb0 = __builtin_amdgcn_mfma_f32_16x16x32_f16(Ah[0][1], R1, pb0, 0,0,0); \
        pa1 = __builtin_amdgcn_mfma_f32_16x16x32_f16(Ah[1][0], R0, pa1, 0,0,0); \
        pb1 = __builtin_amdgcn_mfma_f32_16x16x32_f16(Ah[1][1], R1, pb1, 0,0,0); \
        pa0 = __builtin_amdgcn_mfma_f32_16x16x32_f16(Ra[0][0], B0, pa0, 0,0,0); \
        pb0 = __builtin_amdgcn_mfma_f32_16x16x32_f16(Ra[0][1], B1, pb0, 0,0,0); \
        pa1 = __builtin_amdgcn_mfma_f32_16x16x32_f16(Ra[1][0], B0, pa1, 0,0,0); \
        pb1 = __builtin_amdgcn_mfma_f32_16x16x32_f16(Ra[1][1], B1, pb1, 0,0,0); \
        __builtin_amdgcn_s_setprio(0);                                        \
        const int cbase_ = (CTG) * 16 + m;                                    \
        _Pragma("unroll")                                                     \
        for (int r = 0; r < 4; ++r) {                                         \
            const float q0_ = pa0[r] + pb0[r];                                \
            const int k0_ = ((int)q0_ << 10) | cbase_;                        \
            int m0_;                                                          \
            asm("v_med3_i32 %0, %1, %2, %3"                                   \
                : "=v"(m0_) : "v"(k0_), "v"(d1[0][r]), "v"(d2[0][r]));        \
            d2[0][r] = m0_;                                                   \
            d1[0][r] = (k0_ < d1[0][r]) ? k0_ : d1[0][r];                     \
            const float q1_ = pa1[r] + pb1[r];                                \
            const int k1_ = ((int)q1_ << 10) | cbase_;                        \
            int m1_;                                                          \
            asm("v_med3_i32 %0, %1, %2, %3"                                   \
                : "=v"(m1_) : "v"(k1_), "v"(d1[1][r]), "v"(d2[1][r]));        \
            d2[1][r] = m1_;                                                   \
            d1[1][r] = (k1_ < d1[1][r]) ? k1_ : d1[1][r];                     \
        }                                                                     \
        __builtin_amdgcn_sched_barrier(0x100);  /* only DS_READ may cross */  \
    }

// ring iteration: wait own chunk-T loads (counted), sync, prefetch T+3,
// compute chunk T (2 ct). VMSTR is the counted vmcnt literal.
#define ITER_T(VMSTR, DOSTAGE, T)                                             \
    {                                                                         \
        asm volatile("s_waitcnt " VMSTR ::: "memory");                        \
        __builtin_amdgcn_s_barrier();                                         \
        if (DOSTAGE) STAGE2((T) + 3, (((T) + 3) & 3) * 8192)                  \
        const int base_ = ((T) & 3) * 8192;                                   \
        CT_BODY(base_, 0, (T) * 2)                                            \
        CT_BODY(base_, 1, (T) * 2 + 1)                                        \
    }

__global__ __launch_bounds__(256, 4)
void vq_main(const float* __restrict__ x,
             const float* __restrict__ cb,
             float* __restrict__ ws,
             float* __restrict__ out,
             float* __restrict__ idx_out)
{
    __shared__ f16x8 bbuf[4 * 512];   // 4-slot ring, 8KB (2 ct) per slot
    __shared__ float cnq_lds[1024];   // 2048*||e||^2
    __shared__ int   sk[128];
    __shared__ int   smg[128];

    const int tid  = threadIdx.x;
    const int lane = tid & 63;
    const int wv   = tid >> 6;        // 4 waves, 32 positions each
    const int m    = lane & 15;
    const int q    = lane >> 4;

    const int p0 = blockIdx.x * 128;  // block: 128 consecutive positions
    const int b  = p0 >> 12;
    const int n0 = p0 & (VQ_HW - 1);
    const float* xw = x + (size_t)b * (VQ_D * VQ_HW) + n0 + wv * 32;

    // prologue: stage chunks 0..2 (latency hidden under A build + cn fill)
    STAGE2(0, 0)
    STAGE2(1, 8192)
    STAGE2(2, 16384)

    // cn_q -> LDS (once)
    ((float4*)cnq_lds)[tid] = ((const float4*)(ws + WS_CNQ))[tid];

    // ---- A fragments: hi, 2048*hi (exact), scaled residual; 2 M-tiles ----
    f16x8 Ah[2][2], Ak[2][2], Ra[2][2];
    #pragma unroll
    for (int tl = 0; tl < 2; ++tl)
        #pragma unroll
        for (int ks = 0; ks < 2; ++ks) {
            f16x8 h8, k8, r8;
            #pragma unroll
            for (int j = 0; j < 8; ++j) {
                const float v = xw[(size_t)(ks * 32 + q * 8 + j) * VQ_HW + tl * 16 + m];
                const _Float16 vh = (_Float16)v;
                h8[j] = vh;
                k8[j] = (_Float16)((float)vh * 2048.0f);     // exact (pow2)
                r8[j] = (_Float16)((v - (float)vh) * SC);
            }
            Ah[tl][ks] = h8; Ak[tl][ks] = k8; Ra[tl][ks] = r8;
        }

    int d1[2][4], d2[2][4];
    #pragma unroll
    for (int tl = 0; tl < 2; ++tl)
        #pragma unroll
        for (int r = 0; r < 4; ++r) { d1[tl][r] = 0x7FFFFFFF; d2[tl][r] = 0x7FFFFFFF; }

    const f32x4 zero4 = {0.f, 0.f, 0.f, 0.f};
    const char* lp = (const char*)bbuf + lane * 16;

    __syncthreads();   // one-time full drain: c0-c2 + cn_lds resident

    // ---- main ring: counted vmcnt, loads stay in flight across barriers ----
    for (int t = 0; t < 29; ++t)
        ITER_T("vmcnt(4)", 1, t)      // steady state: wait oldest of 3 chunks
    ITER_T("vmcnt(4)", 0, 29)         // c29: outstanding c29..c31 -> 4
    ITER_T("vmcnt(2)", 0, 30)         // c30: outstanding c30,c31  -> 2
    ITER_T("vmcnt(0)", 0, 31)         // c31: last

    // ---- top-2 merge across the 16 code-columns (keys carry the code) ----
    #pragma unroll
    for (int off = 1; off < 16; off <<= 1)
        #pragma unroll
        for (int tl = 0; tl < 2; ++tl)
            #pragma unroll
            for (int r = 0; r < 4; ++r) {
                const int od1 = __shfl_xor(d1[tl][r], off, 64);
                const int od2 = __shfl_xor(d2[tl][r], off, 64);
                const int mx  = (d1[tl][r] > od1) ? d1[tl][r] : od1;
                const int mn2 = (d2[tl][r] < od2) ? d2[tl][r] : od2;
                d2[tl][r] = (mx < mn2) ? mx : mn2;
                d1[tl][r] = (d1[tl][r] < od1) ? d1[tl][r] : od1;
            }

    if (m == 0) {
        #pragma unroll
        for (int tl = 0; tl < 2; ++tl)
            #pragma unroll
            for (int r = 0; r < 4; ++r) {
                const int li = wv * 32 + tl * 16 + q * 4 + r;
                sk[li]  = d1[tl][r] & 1023;
                smg[li] = (d2[tl][r] >> 10) - (d1[tl][r] >> 10);   // gap, q-units
            }
    }
    __syncthreads();

    // ---- epilogue: indices, rescan flags, quantized scatter ----
    const int pos  = tid & 127;
    const int half = tid >> 7;        // 2 threads per position, 32 dims each
    const int bk   = sk[pos];
    if (half == 0) {
        idx_out[p0 + pos] = (float)bk;
        if (smg[pos] < EPS_Q) {
            const int slot = atomicAdd((int*)ws + WS_CNT, 1);
            ((int*)ws)[WS_LIST + slot] = p0 + pos;
        }
    }
    const float4* cr = (const float4*)(cb + (size_t)bk * VQ_D) + half * 8;
    float* ob = out + (size_t)b * (VQ_D * VQ_HW) + (size_t)(half * 32) * VQ_HW + n0 + pos;
    #pragma unroll
    for (int d4 = 0; d4 < 8; ++d4) {
        const float4 v = cr[d4];
        ob[(size_t)(d4 * 4 + 0) * VQ_HW] = v.x;
        ob[(size_t)(d4 * 4 + 1) * VQ_HW] = v.y;
        ob[(size_t)(d4 * 4 + 2) * VQ_HW] = v.z;
        ob[(size_t)(d4 * 4 + 3) * VQ_HW] = v.w;
    }
}

// ---------- rescan: exact f32 argmin for flagged positions (verified) ----------
__global__ __launch_bounds__(64)
void vq_rescan(const float* __restrict__ x,
               const float* __restrict__ cb,
               const float* __restrict__ ws,
               float* __restrict__ out,
               float* __restrict__ idx_out)
{
    __shared__ float xs[VQ_D];
    const int lane = threadIdx.x;
    const int cnt  = ((const int*)ws)[WS_CNT];
    const int* list = (const int*)ws + WS_LIST;
    const float*  cnb  = ws + WS_CBN;
    const float4* cbT4 = (const float4*)(ws + WS_CBT);

    for (int i = blockIdx.x; i < cnt; i += gridDim.x) {
        const int p = list[i];
        const int b = p >> 12, n = p & (VQ_HW - 1);
        xs[lane] = x[(size_t)b * (VQ_D * VQ_HW) + (size_t)lane * VQ_HW + n];
        __syncthreads();
        float4 xr[16];
        #pragma unroll
        for (int j = 0; j < 16; ++j) xr[j] = ((const float4*)xs)[j];

        float bd = 3.4e38f; int bk = 0;
        #pragma unroll 4
        for (int t = 0; t < 16; ++t) {
            const int code = t * 64 + lane;           // per-lane ascending
            float a0 = 0.f, a1 = 0.f, a2 = 0.f, a3 = 0.f;
            #pragma unroll
            for (int j4 = 0; j4 < 16; ++j4) {
                const float4 c = cbT4[j4 * 1024 + code];   // coalesced
                a0 = fmaf(xr[j4].x, c.x, a0); a1 = fmaf(xr[j4].y, c.y, a1);
                a2 = fmaf(xr[j4].z, c.z, a2); a3 = fmaf(xr[j4].w, c.w, a3);
            }
            const float dist = fmaf(-2.0f, (a0 + a1) + (a2 + a3), cnb[code]);
            if (dist < bd) { bd = dist; bk = code; }
        }
        #pragma unroll
        for (int off = 1; off < 64; off <<= 1) {      // min dist, tie -> min k
            const float od = __shfl_xor(bd, off, 64);
            const int   ok = __shfl_xor(bk, off, 64);
            if (od < bd || (od == bd && ok < bk)) { bd = od; bk = ok; }
        }
        out[(size_t)b * (VQ_D * VQ_HW) + (size_t)lane * VQ_HW + n] = cb[(size_t)bk * VQ_D + lane];
        if (lane == 0) idx_out[p] = (float)bk;
        __syncthreads();
    }
}

extern "C" void kernel_launch(void* const* d_in, const int* in_sizes, int n_in,
                              void* d_out, int out_size, void* d_ws, size_t ws_size,
                              hipStream_t stream) {
    const float* x  = (const float*)d_in[0];
    const float* cb = (const float*)d_in[1];
    float* out = (float*)d_out;
    float* idx = out + (size_t)VQ_NPOS * VQ_D;   // 8,388,608 floats in
    float* ws  = (float*)d_ws;                    // ~1.06 MB used

    vq_prep  <<<dim3(132),  dim3(256), 0, stream>>>(cb, ws);
    vq_main  <<<dim3(1024), dim3(256), 0, stream>>>(x, cb, ws, out, idx);
    vq_rescan<<<dim3(1024), dim3(64),  0, stream>>>(x, cb, ws, out, idx);
}

// Round 9
// 155.389 us; speedup vs baseline: 1.5726x; 1.0203x over previous
//
#include <hip/hip_runtime.h>

// VectorQuantizer: x (32,64,64,64) f32, codebook (1024,64) f32
// out = concat( quantized (32,64,64,64) f32 , indices (32,64,64) as f32 )
//
// R14 = R13's ring + verified math, 4 M-tiles/wave (64 pos) for M-amortization.
//  - R13 post-mortem: counted-vmcnt ring + setprio = NULL (68-70us, Mfma 30-33
//    = R12 = R10). Barrier-drain theory falsified. MfmaUtil pinned ~30%
//    across occupancy/ILP/pipeline variations => per-wave phase mix is the
//    limiter: per ct {4 ds_read +120cy lat}{12 MFMA=466cy}{~90cy VALU},
//    lockstep waves burst each pipe serially; MFMA = ~40% of wave cycle.
//  - Fix the FRACTION: 4 M-tiles/wave -> same LDS/cn per ct feeds 24 MFMAs
//    (932cy); matrix fraction ~62%; per-CU LDS read traffic halves.
//    VGPR ~190 -> 2 blocks/CU (8 waves), grid 512, launch_bounds(256,2).
//  - ring/staging/prep/rescan identical to R13 (verified). Math bit-identical
//    (q-unit int keys, EPS_Q 24, pa/pb split by K-half, exact-f32 rescan).
//  - spill tripwire: FETCH ~18.5MB / WRITE ~33MB must hold (R11 lesson);
//    sched_barrier(0x100) fence per body bounds acc live ranges.

typedef _Float16 f16x8 __attribute__((ext_vector_type(8)));
typedef float    f32x4 __attribute__((ext_vector_type(4)));

#define VQ_D    64
#define VQ_HW   4096
#define VQ_NPOS 131072
#define SC      2048.0f
#define EPS_Q   24         // flag margin in q-units (24/2048 = 1.17e-2)
// ws float offsets (stream = 32 chunks * 8192B = 256KB = 65536 floats)
#define WS_CBN  65536      // f32 cn[1024] raw (rescan)
#define WS_CNQ  66560      // f32 cn_q[1024] = 2048*cn (main C-init)
#define WS_CBT  67584      // float4 cbT4[16384] (256 KB)
#define WS_CNT  133120     // int rescan counter
#define WS_LIST 133124     // int list[131072]

// ---------- prep (identical to R13, verified) ----------
__global__ __launch_bounds__(256)
void vq_prep(const float* __restrict__ cb, float* __restrict__ ws)
{
    const int tid = threadIdx.x;
    const int blk = blockIdx.x;
    if (blk < 64) {
        const int it   = blk * 256 + tid;            // [0, 16384)
        const int ct   = it >> 8;
        const int s    = (it >> 6) & 3;
        const int lane = it & 63;
        const int ks   = s & 1, isR = s >> 1;
        const int n    = ct * 16 + (lane & 15);      // code (B column)
        const int k0   = ks * 32 + (lane >> 4) * 8;  // dim  (B row)
        const float* src = cb + n * 64 + k0;
        f16x8 o;
        #pragma unroll
        for (int j = 0; j < 8; ++j) {
            const float b = src[j];
            const _Float16 bh = (_Float16)b;
            o[j] = isR ? (_Float16)((b - (float)bh) * (-2.0f * SC))
                       : (_Float16)(-2.0f * (float)bh);
        }
        ((f16x8*)ws)[it] = o;
    } else if (blk < 128) {
        const int it = (blk - 64) * 256 + tid;       // [0, 16384)
        const int k = it >> 4, j4 = it & 15;
        ((float4*)(ws + WS_CBT))[j4 * 1024 + k] = ((const float4*)cb)[it];
    } else {
        const int k = (blk - 128) * 256 + tid;       // [0, 1024)
        const float4* row = (const float4*)(cb + k * 64);
        float a0 = 0.f, a1 = 0.f, a2 = 0.f, a3 = 0.f;
        #pragma unroll
        for (int j = 0; j < 16; ++j) {
            const float4 c = row[j];
            a0 = fmaf(c.x, c.x, a0); a1 = fmaf(c.y, c.y, a1);
            a2 = fmaf(c.z, c.z, a2); a3 = fmaf(c.w, c.w, a3);
        }
        const float cn = (a0 + a1) + (a2 + a3);
        ws[WS_CBN + k] = cn;                         // raw (rescan)
        ws[WS_CNQ + k] = cn * 2048.0f;               // q-units (main)
        if (k == 0) ((int*)ws)[WS_CNT] = 0;
    }
}

// ---------- main ----------
#define GLOAD_LDS(GP, LP)                                                     \
    __builtin_amdgcn_global_load_lds(                                         \
        (const __attribute__((address_space(1))) unsigned int*)(GP),          \
        (__attribute__((address_space(3))) unsigned int*)(LP), 16, 0, 0)

// stage 8KB chunk CK into ring slot byte-offset BOFF: 2 gloads per wave
#define STAGE2(CK, BOFF)                                                      \
    {                                                                         \
        const char* gs_ = (const char*)ws + (size_t)(CK) * 8192               \
                          + wv * 2048 + lane * 16;                            \
        char* ld_ = (char*)bbuf + (BOFF) + wv * 2048;                         \
        GLOAD_LDS(gs_, ld_);                                                  \
        GLOAD_LDS(gs_ + 1024, ld_ + 1024);                                    \
    }

// one 16-code tile, 4 M-tiles: 8 independent depth-3 chains (pa/pb per tile),
// 24 MFMAs; then 1 add + int-key update per output (16 outputs).
#define CT_BODY(BOFF, CI, CTG)                                                \
    {                                                                         \
        const f16x8 B0 = *(const f16x8*)(lp + (BOFF) + (CI) * 4096);          \
        const f16x8 B1 = *(const f16x8*)(lp + (BOFF) + (CI) * 4096 + 1024);   \
        const f16x8 R0 = *(const f16x8*)(lp + (BOFF) + (CI) * 4096 + 2048);   \
        const f16x8 R1 = *(const f16x8*)(lp + (BOFF) + (CI) * 4096 + 3072);   \
        const float cvq = cnq_lds[(CTG) * 16 + m];                            \
        const f32x4 Ci = {cvq, cvq, cvq, cvq};                                \
        f32x4 pa[4], pb[4];                                                   \
        __builtin_amdgcn_s_setprio(1);                                        \
        _Pragma("unroll")                                                     \
        for (int tl = 0; tl < 4; ++tl) {                                      \
            pa[tl] = __builtin_amdgcn_mfma_f32_16x16x32_f16(Ak[tl][0], B0, Ci,    0,0,0); \
            pb[tl] = __builtin_amdgcn_mfma_f32_16x16x32_f16(Ak[tl][1], B1, zero4, 0,0,0); \
        }                                                                     \
        _Pragma("unroll")                                                     \
        for (int tl = 0; tl < 4; ++tl) {                                      \
            pa[tl] = __builtin_amdgcn_mfma_f32_16x16x32_f16(Ah[tl][0], R0, pa[tl], 0,0,0); \
            pb[tl] = __builtin_amdgcn_mfma_f32_16x16x32_f16(Ah[tl][1], R1, pb[tl], 0,0,0); \
        }                                                                     \
        _Pragma("unroll")                                                     \
        for (int tl = 0; tl < 4; ++tl) {                                      \
            pa[tl] = __builtin_amdgcn_mfma_f32_16x16x32_f16(Ra[tl][0], B0, pa[tl], 0,0,0); \
            pb[tl] = __builtin_amdgcn_mfma_f32_16x16x32_f16(Ra[tl][1], B1, pb[tl], 0,0,0); \
        }                                                                     \
        __builtin_amdgcn_s_setprio(0);                                        \
        const int cbase_ = (CTG) * 16 + m;                                    \
        _Pragma("unroll")                                                     \
        for (int tl = 0; tl < 4; ++tl)                                        \
            _Pragma("unroll")                                                 \
            for (int r = 0; r < 4; ++r) {                                     \
                const float q_ = pa[tl][r] + pb[tl][r];                       \
                const int k_ = ((int)q_ << 10) | cbase_;                      \
                int md_;                                                      \
                asm("v_med3_i32 %0, %1, %2, %3"                               \
                    : "=v"(md_) : "v"(k_), "v"(d1[tl][r]), "v"(d2[tl][r]));   \
                d2[tl][r] = md_;                                              \
                d1[tl][r] = (k_ < d1[tl][r]) ? k_ : d1[tl][r];                \
            }                                                                 \
        __builtin_amdgcn_sched_barrier(0x100);  /* only DS_READ may cross */  \
    }

// ring iteration: wait own chunk-T loads (counted), sync, prefetch T+3,
// compute chunk T (2 ct). VMSTR is the counted vmcnt literal.
#define ITER_T(VMSTR, DOSTAGE, T)                                             \
    {                                                                         \
        asm volatile("s_waitcnt " VMSTR ::: "memory");                        \
        __builtin_amdgcn_s_barrier();                                         \
        if (DOSTAGE) STAGE2((T) + 3, (((T) + 3) & 3) * 8192)                  \
        const int base_ = ((T) & 3) * 8192;                                   \
        CT_BODY(base_, 0, (T) * 2)                                            \
        CT_BODY(base_, 1, (T) * 2 + 1)                                        \
    }

__global__ __launch_bounds__(256, 2)
void vq_main(const float* __restrict__ x,
             const float* __restrict__ cb,
             float* __restrict__ ws,
             float* __restrict__ out,
             float* __restrict__ idx_out)
{
    __shared__ f16x8 bbuf[4 * 512];   // 4-slot ring, 8KB (2 ct) per slot
    __shared__ float cnq_lds[1024];   // 2048*||e||^2
    __shared__ int   sk[256];
    __shared__ int   smg[256];

    const int tid  = threadIdx.x;
    const int lane = tid & 63;
    const int wv   = tid >> 6;        // 4 waves, 64 positions each
    const int m    = lane & 15;
    const int q    = lane >> 4;

    const int p0 = blockIdx.x * 256;  // block: 256 consecutive positions
    const int b  = p0 >> 12;
    const int n0 = p0 & (VQ_HW - 1);
    const float* xw = x + (size_t)b * (VQ_D * VQ_HW) + n0 + wv * 64;

    // prologue: stage chunks 0..2 (latency hidden under A build + cn fill)
    STAGE2(0, 0)
    STAGE2(1, 8192)
    STAGE2(2, 16384)

    // cn_q -> LDS (once)
    ((float4*)cnq_lds)[tid] = ((const float4*)(ws + WS_CNQ))[tid];

    // ---- A fragments: hi, 2048*hi (exact), scaled residual; 4 M-tiles ----
    f16x8 Ah[4][2], Ak[4][2], Ra[4][2];
    #pragma unroll
    for (int tl = 0; tl < 4; ++tl)
        #pragma unroll
        for (int ks = 0; ks < 2; ++ks) {
            f16x8 h8, k8, r8;
            #pragma unroll
            for (int j = 0; j < 8; ++j) {
                const float v = xw[(size_t)(ks * 32 + q * 8 + j) * VQ_HW + tl * 16 + m];
                const _Float16 vh = (_Float16)v;
                h8[j] = vh;
                k8[j] = (_Float16)((float)vh * 2048.0f);     // exact (pow2)
                r8[j] = (_Float16)((v - (float)vh) * SC);
            }
            Ah[tl][ks] = h8; Ak[tl][ks] = k8; Ra[tl][ks] = r8;
        }

    int d1[4][4], d2[4][4];
    #pragma unroll
    for (int tl = 0; tl < 4; ++tl)
        #pragma unroll
        for (int r = 0; r < 4; ++r) { d1[tl][r] = 0x7FFFFFFF; d2[tl][r] = 0x7FFFFFFF; }

    const f32x4 zero4 = {0.f, 0.f, 0.f, 0.f};
    const char* lp = (const char*)bbuf + lane * 16;

    __syncthreads();   // one-time full drain: c0-c2 + cn_lds resident

    // ---- main ring: counted vmcnt, loads stay in flight across barriers ----
    for (int t = 0; t < 29; ++t)
        ITER_T("vmcnt(4)", 1, t)      // steady state: wait oldest of 3 chunks
    ITER_T("vmcnt(4)", 0, 29)         // c29: outstanding c29..c31 -> 4
    ITER_T("vmcnt(2)", 0, 30)         // c30: outstanding c30,c31  -> 2
    ITER_T("vmcnt(0)", 0, 31)         // c31: last

    // ---- top-2 merge across the 16 code-columns (keys carry the code) ----
    #pragma unroll
    for (int off = 1; off < 16; off <<= 1)
        #pragma unroll
        for (int tl = 0; tl < 4; ++tl)
            #pragma unroll
            for (int r = 0; r < 4; ++r) {
                const int od1 = __shfl_xor(d1[tl][r], off, 64);
                const int od2 = __shfl_xor(d2[tl][r], off, 64);
                const int mx  = (d1[tl][r] > od1) ? d1[tl][r] : od1;
                const int mn2 = (d2[tl][r] < od2) ? d2[tl][r] : od2;
                d2[tl][r] = (mx < mn2) ? mx : mn2;
                d1[tl][r] = (d1[tl][r] < od1) ? d1[tl][r] : od1;
            }

    if (m == 0) {
        #pragma unroll
        for (int tl = 0; tl < 4; ++tl)
            #pragma unroll
            for (int r = 0; r < 4; ++r) {
                const int li = wv * 64 + tl * 16 + q * 4 + r;
                sk[li]  = d1[tl][r] & 1023;
                smg[li] = (d2[tl][r] >> 10) - (d1[tl][r] >> 10);   // gap, q-units
            }
    }
    __syncthreads();

    // ---- epilogue: indices, rescan flags, quantized scatter ----
    const int bk = sk[tid];           // 1 thread per position
    idx_out[p0 + tid] = (float)bk;
    if (smg[tid] < EPS_Q) {
        const int slot = atomicAdd((int*)ws + WS_CNT, 1);
        ((int*)ws)[WS_LIST + slot] = p0 + tid;
    }
    const float4* cr = (const float4*)(cb + (size_t)bk * VQ_D);
    float* ob = out + (size_t)b * (VQ_D * VQ_HW) + n0 + tid;
    #pragma unroll
    for (int d4 = 0; d4 < 16; ++d4) {
        const float4 v = cr[d4];
        ob[(size_t)(d4 * 4 + 0) * VQ_HW] = v.x;
        ob[(size_t)(d4 * 4 + 1) * VQ_HW] = v.y;
        ob[(size_t)(d4 * 4 + 2) * VQ_HW] = v.z;
        ob[(size_t)(d4 * 4 + 3) * VQ_HW] = v.w;
    }
}

// ---------- rescan: exact f32 argmin for flagged positions (verified) ----------
__global__ __launch_bounds__(64)
void vq_rescan(const float* __restrict__ x,
               const float* __restrict__ cb,
               const float* __restrict__ ws,
               float* __restrict__ out,
               float* __restrict__ idx_out)
{
    __shared__ float xs[VQ_D];
    const int lane = threadIdx.x;
    const int cnt  = ((const int*)ws)[WS_CNT];
    const int* list = (const int*)ws + WS_LIST;
    const float*  cnb  = ws + WS_CBN;
    const float4* cbT4 = (const float4*)(ws + WS_CBT);

    for (int i = blockIdx.x; i < cnt; i += gridDim.x) {
        const int p = list[i];
        const int b = p >> 12, n = p & (VQ_HW - 1);
        xs[lane] = x[(size_t)b * (VQ_D * VQ_HW) + (size_t)lane * VQ_HW + n];
        __syncthreads();
        float4 xr[16];
        #pragma unroll
        for (int j = 0; j < 16; ++j) xr[j] = ((const float4*)xs)[j];

        float bd = 3.4e38f; int bk = 0;
        #pragma unroll 4
        for (int t = 0; t < 16; ++t) {
            const int code = t * 64 + lane;           // per-lane ascending
            float a0 = 0.f, a1 = 0.f, a2 = 0.f, a3 = 0.f;
            #pragma unroll
            for (int j4 = 0; j4 < 16; ++j4) {
                const float4 c = cbT4[j4 * 1024 + code];   // coalesced
                a0 = fmaf(xr[j4].x, c.x, a0); a1 = fmaf(xr[j4].y, c.y, a1);
                a2 = fmaf(xr[j4].z, c.z, a2); a3 = fmaf(xr[j4].w, c.w, a3);
            }
            const float dist = fmaf(-2.0f, (a0 + a1) + (a2 + a3), cnb[code]);
            if (dist < bd) { bd = dist; bk = code; }
        }
        #pragma unroll
        for (int off = 1; off < 64; off <<= 1) {      // min dist, tie -> min k
            const float od = __shfl_xor(bd, off, 64);
            const int   ok = __shfl_xor(bk, off, 64);
            if (od < bd || (od == bd && ok < bk)) { bd = od; bk = ok; }
        }
        out[(size_t)b * (VQ_D * VQ_HW) + (size_t)lane * VQ_HW + n] = cb[(size_t)bk * VQ_D + lane];
        if (lane == 0) idx_out[p] = (float)bk;
        __syncthreads();
    }
}

extern "C" void kernel_launch(void* const* d_in, const int* in_sizes, int n_in,
                              void* d_out, int out_size, void* d_ws, size_t ws_size,
                              hipStream_t stream) {
    const float* x  = (const float*)d_in[0];
    const float* cb = (const float*)d_in[1];
    float* out = (float*)d_out;
    float* idx = out + (size_t)VQ_NPOS * VQ_D;   // 8,388,608 floats in
    float* ws  = (float*)d_ws;                    // ~1.06 MB used

    vq_prep  <<<dim3(132),  dim3(256), 0, stream>>>(cb, ws);
    vq_main  <<<dim3(512),  dim3(256), 0, stream>>>(x, cb, ws, out, idx);
    vq_rescan<<<dim3(1024), dim3(64),  0, stream>>>(x, cb, ws, out, idx);
}